// Round 22
// baseline (133.252 us; speedup 1.0000x reference)
//
#include <hip/hip_runtime.h>
#include <math.h>

#define BB 8
#define CC 128
#define HH 64
#define WW 64
#define NPTS 9
#define OUTC 256
#define HW (HH*WW)
#define KTOT (CC*NPTS)   // 1152
#define BK 288           // 32 channels * 9 taps per K-chunk
#define AP 290           // Atile row in bf16 elems: 145 words (ODD -> bank spread)
#define WROWS 6          // x row window: global rows h-2 .. h+3

typedef __attribute__((ext_vector_type(8))) short bf16x8;
typedef __attribute__((ext_vector_type(4))) float f32x4;

// bf16 weights, k-order permuted (UNCHANGED from R21): k = cb*288 + pair*18
// + n*2 + half, channel c = cb*32 + pair*2 + half, tap n = ky*3+kx.
__device__ unsigned short g_wT[OUTC * KTOT];   // main conv weights
__device__ unsigned short g_woT[32 * KTOT];    // offset(18)+mask(9)+zero(5)

__device__ __forceinline__ unsigned short f2bf(float f) {
    unsigned int u = __builtin_bit_cast(unsigned int, f);
    unsigned int r = (u + 0x7FFFu + ((u >> 16) & 1u)) >> 16;   // RNE
    return (unsigned short)r;
}

__device__ __forceinline__ unsigned cvtpk(float lo, float hi) {   // {bf16(lo), bf16(hi)<<16}
    unsigned r;
    asm("v_cvt_pk_bf16_f32 %0, %1, %2" : "=v"(r) : "v"(lo), "v"(hi));
    return r;
}
__device__ __forceinline__ float bflo(unsigned w) { return __builtin_bit_cast(float, w << 16); }
__device__ __forceinline__ float bfhi(unsigned w) { return __builtin_bit_cast(float, w & 0xFFFF0000u); }

__device__ __forceinline__ int orig_k(int k) {      // permuted k -> original c*9+n
    int cb = k / BK, r = k % BK;
    int pair = r / 18, r2 = r % 18;
    int n = r2 >> 1, half = r2 & 1;
    return (cb * 32 + pair * 2 + half) * NPTS + n;
}

__global__ __launch_bounds__(256) void prep_kernel(
    const float* __restrict__ wo, const float* __restrict__ wm,
    const float* __restrict__ wc)
{
    int idx = blockIdx.x * 256 + threadIdx.x;
    const int T1 = 32 * KTOT;
    if (idx < T1) {
        int nn = idx / KTOT, k = idx - nn * KTOT;
        int ok = orig_k(k);
        float v = (nn < 18) ? wo[nn * KTOT + ok]
                            : (nn < 27 ? wm[(nn - 18) * KTOT + ok] : 0.f);
        g_woT[idx] = f2bf(v);
    } else if (idx < T1 + OUTC * KTOT) {
        int j = idx - T1;
        int oc = j / KTOT, k = j - oc * KTOT;
        g_wT[j] = f2bf(wc[oc * KTOT + orig_k(k)]);
    }
}

// Quad staging (R12/R21-proven, UNCHANGED): wave w stages quad w (channels
// cb*32+4w..+3), full 64 columns. PF = 6 uint2 = 12 VGPRs.
struct PF { uint2 w[WROWS]; };

__device__ __forceinline__ void issue(PF& pf, const float* __restrict__ xb,
                                      int h, int cb, int tid) {
    if (cb < 0 || cb > 3) return;
    int q = tid >> 6, col = tid & 63;         // q = wave id
    const float* base = xb + (size_t)(cb * 32 + 4 * q) * HW + col;
    #pragma unroll
    for (int r = 0; r < WROWS; ++r) {
        int gr = h - 2 + r;
        bool v = (gr >= 0) & (gr < HH);
        float a0 = v ? base[0 * HW + gr * WW] : 0.f;
        float a1 = v ? base[1 * HW + gr * WW] : 0.f;
        float a2 = v ? base[2 * HW + gr * WW] : 0.f;
        float a3 = v ? base[3 * HW + gr * WW] : 0.f;
        pf.w[r].x = cvtpk(a0, a1);
        pf.w[r].y = cvtpk(a2, a3);
    }
}

__device__ __forceinline__ void commit(uint2* win, const PF& pf, int tid) {
    uint2* wp = win + (tid >> 6) * 384 + (tid & 63);
    #pragma unroll
    for (int r = 0; r < WROWS; ++r) wp[r * 64] = pf.w[r];   // ds_write_b64
}

// M=32 half-row blocks: grid 1024 = (b, h, half), 512 threads = 8 waves.
// LDS 48.9 KB -> 3 blocks/CU = 24 waves/CU in THREE independent barrier
// groups (R21 had two). Siblings duplicate only window STAGING (global
// loads, L2-served); build/params/MFMA are fully partitioned (R13/R16
// lesson respected). Weight layout, staging, K order = R21 verbatim ->
// numerics bit-identical to R21 (absmax must be 0.015625).
__global__ __launch_bounds__(512) __attribute__((amdgpu_waves_per_eu(4, 8)))
void fused_kernel(
    const float* __restrict__ x,
    const float* __restrict__ b_offset, const float* __restrict__ b_mask,
    const float* __restrict__ bn_gamma, const float* __restrict__ bn_beta,
    const float* __restrict__ bn_mean,  const float* __restrict__ bn_var,
    float* __restrict__ out)
{
    __shared__ unsigned short Atile[32][AP];     // 18560 B (no pad words: every
                                                 // data word rewritten per phase)
    __shared__ uint2 win[8 * 384];               // 24576 B quad-packed bf16 window
    __shared__ float4 gtab[NPTS][32];            //  4608 B bilinear weights
    __shared__ uint2  otab[NPTS][32];            //  2304 B 4 x u16 offsets
    // px/py/m overlay lives in ATILE (dead between pass-A MFMA and pass-B
    // build); the staged window survives the A->B transition (cb3 resident).
    float* ovf = (float*)&Atile[0][0];           // 3456 B used

    // XCD swizzle: batch b pinned to XCD; siblings (h,0),(h,1) adjacent.
    int bid = blockIdx.x;
    int b = bid & 7;
    int rr = bid >> 3;                           // 0..127
    int h = rr >> 1, half = rr & 1;
    int tid  = threadIdx.x;
    int lane = tid & 63;
    int wv   = __builtin_amdgcn_readfirstlane(tid >> 6);  // wave 0..7
    int l15  = lane & 15;
    int kg   = lane >> 4;
    int p    = lane & 31;                        // local pixel/row 0..31
    int ps   = lane >> 5;                        // pair-select within quad
    int pairIdx = wv * 2 + ps;                   // 0..15 (32 ch = 16 pairs)

    const float* xb = x + (size_t)b * CC * HW;
    unsigned* AtU = (unsigned*)&Atile[0][0];     // row stride 145 words (odd)
    const unsigned* wu = (const unsigned*)(win + wv * 384);

    // ================= PASS A: offset/mask conv (M=32,N=32,K=1152) =========
    // MFMA by waves 0..3: (mi_a, nf_a) = (wv&1, (wv>>1)&1). Waves 4..7 idle
    // at MFMA (they still stage + build).
    int mi_a = wv & 1, nf_a = (wv >> 1) & 1;
    f32x4 s1acc = {0.f, 0.f, 0.f, 0.f};

    PF pf; issue(pf, xb, h, 0, tid);
    for (int cb = 0; cb < 4; ++cb) {
        commit(win, pf, tid);                // wave-private: no barrier needed
        {   // 3x3 patch for this thread's pair (global col = half*32+p+kx-1)
            #pragma unroll
            for (int tap = 0; tap < 9; ++tap) {
                int ky = tap / 3, kx = tap % 3;
                int gcol = half * 32 + p + kx - 1;
                int colc = min(max(gcol, 0), WW - 1);
                unsigned w = wu[((ky + 1) * 64 + colc) * 2 + ps];
                w = (gcol >= 0 && gcol < WW) ? w : 0u;
                AtU[p * 145 + pairIdx * 9 + tap] = w;
            }
        }
        // prefetch: cb+1 for cb<3; at cb==3 prefetch cb2 (pass B runs 3,2,1,0
        // and phase 3 uses the RESIDENT window).
        issue(pf, xb, h, (cb < 3) ? cb + 1 : 2, tid);
        __syncthreads();                     // Atile complete
        __builtin_amdgcn_s_setprio(1);
        if (wv < 4) {
            for (int q = 0; q < 9; ++q) {
                int koff = q * 32 + kg * 8;
                bf16x8 af = *(const bf16x8*)&Atile[mi_a * 16 + l15][koff];
                int nn = nf_a * 16 + l15;
                bf16x8 bfr = *(const bf16x8*)&g_woT[nn * KTOT + cb * BK + koff];
                s1acc = __builtin_amdgcn_mfma_f32_16x16x32_bf16(af, bfr, s1acc, 0, 0, 0);
            }
        }
        __builtin_amdgcn_s_setprio(0);
        __syncthreads();                     // MFMA done; next build may overwrite
    }

    // ---- pass-A epilogue into Atile overlay (Atile dead; win kept!) --------
    // layout: px at ovf[0..287], py at ovf[288..575], m at ovf[576..863]
    if (wv < 4) {
        #pragma unroll
        for (int j = 0; j < 4; ++j) {
            float val = s1acc[j];
            int nn   = nf_a * 16 + l15;
            int pixl = mi_a * 16 + kg * 4 + j;   // local pixel 0..31
            if (nn < 9) {
                ovf[nn * 32 + pixl] = val + b_offset[nn] + (float)(nn / 3 - 1) + (float)(h + 1);
            } else if (nn < 18) {
                int n = nn - 9;
                ovf[288 + n * 32 + pixl] = val + b_offset[nn] + (float)(n % 3 - 1)
                                         + (float)(half * 32 + pixl + 1);
            } else if (nn < 27) {
                int n = nn - 18;
                float sg = val + b_mask[n];
                ovf[576 + n * 32 + pixl] = 1.f / (1.f + expf(-sg));
            }
        }
    }
    __syncthreads();

    // ================= param tables: WAVE-PARALLEL (n = wv; wave0 also n=8) =
    // Same algebra as R21; lanes 0..31 of each wave, t = local pixel.
    for (int n = wv; n < NPTS; n += 8) {
        if (lane < 32) {
            int t = lane;
            float px = ovf[n * 32 + t];
            float py = ovf[288 + n * 32 + t];
            float m  = ovf[576 + n * 32 + t];
            float fx = floorf(px), fy = floorf(py);
            float qltx = fminf(fmaxf(fx,       0.f), 65.f);
            float qlty = fminf(fmaxf(fy,       0.f), 65.f);
            float qrbx = fminf(fmaxf(fx + 1.f, 0.f), 65.f);
            float qrby = fminf(fmaxf(fy + 1.f, 0.f), 65.f);
            float pxc  = fminf(fmaxf(px, 0.f), 65.f);
            float pyc  = fminf(fmaxf(py, 0.f), 65.f);
            float glt = (1.f + (qltx - pxc)) * (1.f + (qlty - pyc)) * m;
            float grb = (1.f - (qrbx - pxc)) * (1.f - (qrby - pyc)) * m;
            float glb = (1.f + (qltx - pxc)) * (1.f - (qrby - pyc)) * m;
            float grt = (1.f - (qrbx - pxc)) * (1.f + (qlty - pyc)) * m;
            int i0 = (int)qltx - 1, j0 = (int)qlty - 1;
            int i1 = (int)qrbx - 1, j1 = (int)qrby - 1;
            bool v00 = (i0 >= 0) & (i0 < HH) & (j0 >= 0) & (j0 < WW);
            bool v11 = (i1 >= 0) & (i1 < HH) & (j1 >= 0) & (j1 < WW);
            bool v01 = (i0 >= 0) & (i0 < HH) & (j1 >= 0) & (j1 < WW);
            bool v10 = (i1 >= 0) & (i1 < HH) & (j0 >= 0) & (j0 < WW);
            float4 g;
            g.x = v00 ? glt : 0.f;   // (i0,j0)
            g.y = v11 ? grb : 0.f;   // (i1,j1)
            g.z = v01 ? glb : 0.f;   // (i0,j1)
            g.w = v10 ? grt : 0.f;   // (i1,j0)
            gtab[n][t] = g;
            bool okr0 = ((i0 >= h - 2) & (i0 <= h + 3)) | !(v00 | v01);
            bool okr1 = ((i1 >= h - 2) & (i1 <= h + 3)) | !(v11 | v10);
            bool ok = okr0 & okr1;
            int r0w = min(max(i0 - (h - 2), 0), WROWS - 1);
            int r1w = min(max(i1 - (h - 2), 0), WROWS - 1);
            int r0g = min(max(i0, 0), HH - 1);
            int r1g = min(max(i1, 0), HH - 1);
            int j0c = min(max(j0, 0), WW - 1);
            int j1c = min(max(j1, 0), WW - 1);
            int o  = ok ? (r0w * WW + j0c) : (r0g * WW + j0c);
            int dr = ok ? (r1w - r0w) : (r1g - r0g);
            int dj = j1c - j0c;
            unsigned o00 = (unsigned)o;
            unsigned o11 = (unsigned)(o + dr * WW + dj);
            unsigned o01 = (unsigned)(o + dj);
            unsigned o10 = (unsigned)(o + dr * WW);
            uint2 ot;
            ot.x = (o00 | (ok ? 0u : 0x8000u)) | (o11 << 16);
            ot.y = o01 | (o10 << 16);
            otab[n][t] = ot;
        }
    }
    __syncthreads();                         // params ready; ovf (in Atile) dead

    // ================= PASS B: main GEMM, K order 3,2,1,0 ===================
    // Phase 3 builds from the window left resident by pass A; pf holds cb2.
    f32x4 acc[2][2];
    #pragma unroll
    for (int mi = 0; mi < 2; ++mi)
        #pragma unroll
        for (int ni = 0; ni < 2; ++ni)
            acc[mi][ni] = (f32x4){0.f, 0.f, 0.f, 0.f};

    int oc0 = wv * 32;

    for (int j = 0; j < 4; ++j) {
        int cb = 3 - j;                      // chunk built + consumed this phase
        if (j > 0) {
            commit(win, pf, tid);            // window for this cb (wave-private)
            issue(pf, xb, h, cb - 1, tid);   // prefetch next (guard skips -1)
        }
        {   // bilinear build for this thread's pair (2 channels)
            const float* xgA = xb + (size_t)(cb * 32 + pairIdx * 2) * HW;
            const float* xgB = xgA + HW;
            #pragma unroll
            for (int n = 0; n < NPTS; ++n) {
                float4 g  = gtab[n][p];      // lanes p/p+32 same addr -> broadcast
                uint2  ot = otab[n][p];
                int o00 = ot.x & 0x7FFF;
                int o11 = ot.x >> 16;
                int o01 = ot.y & 0xFFFF;
                int o10 = ot.y >> 16;
                float v0, v1;
                if (!(ot.x & 0x8000u)) {     // in-window: pair b32 gathers
                    unsigned w00 = wu[o00 * 2 + ps];
                    unsigned w11 = wu[o11 * 2 + ps];
                    unsigned w01 = wu[o01 * 2 + ps];
                    unsigned w10 = wu[o10 * 2 + ps];
                    v0 =       g.x * bflo(w00);
                    v0 = fmaf(g.y, bflo(w11), v0);
                    v0 = fmaf(g.z, bflo(w01), v0);
                    v0 = fmaf(g.w, bflo(w10), v0);
                    v1 =       g.x * bfhi(w00);
                    v1 = fmaf(g.y, bfhi(w11), v1);
                    v1 = fmaf(g.z, bfhi(w01), v1);
                    v1 = fmaf(g.w, bfhi(w10), v1);
                } else {                     // rare: f32 global corners
                    v0 =       g.x * xgA[o00];
                    v0 = fmaf(g.y, xgA[o11], v0);
                    v0 = fmaf(g.z, xgA[o01], v0);
                    v0 = fmaf(g.w, xgA[o10], v0);
                    v1 =       g.x * xgB[o00];
                    v1 = fmaf(g.y, xgB[o11], v1);
                    v1 = fmaf(g.z, xgB[o01], v1);
                    v1 = fmaf(g.w, xgB[o10], v1);
                }
                AtU[p * 145 + pairIdx * 9 + n] = cvtpk(v0, v1);
            }
        }
        __syncthreads();                     // Atile complete
        __builtin_amdgcn_s_setprio(1);
        for (int q = 0; q < 9; ++q) {
            int koff = q * 32 + kg * 8;
            bf16x8 af[2];
            #pragma unroll
            for (int mi = 0; mi < 2; ++mi)
                af[mi] = *(const bf16x8*)&Atile[mi * 16 + l15][koff];
            #pragma unroll
            for (int ni = 0; ni < 2; ++ni) {
                int oc = oc0 + ni * 16 + l15;
                bf16x8 bfr = *(const bf16x8*)&g_wT[oc * KTOT + cb * BK + koff];
                #pragma unroll
                for (int mi = 0; mi < 2; ++mi)
                    acc[mi][ni] = __builtin_amdgcn_mfma_f32_16x16x32_bf16(af[mi], bfr, acc[mi][ni], 0, 0, 0);
            }
        }
        __builtin_amdgcn_s_setprio(0);
        __syncthreads();                     // MFMA done; next build may overwrite
    }

    // ================= epilogue: BN + ReLU, float4 stores ===================
    #pragma unroll
    for (int ni = 0; ni < 2; ++ni) {
        int oc = oc0 + ni * 16 + l15;
        float inv   = 1.f / sqrtf(bn_var[oc] + 1e-5f);
        float scale = bn_gamma[oc] * inv;
        float shift = bn_beta[oc] - bn_mean[oc] * scale;
        float* op = out + ((size_t)b * OUTC + oc) * HW + h * WW + half * 32 + kg * 4;
        #pragma unroll
        for (int mi = 0; mi < 2; ++mi) {
            f32x4 o4;
            #pragma unroll
            for (int jj = 0; jj < 4; ++jj) {
                float v = fmaf(acc[mi][ni][jj], scale, shift);
                o4[jj] = v > 0.f ? v : 0.f;
            }
            *(f32x4*)(op + mi * 16) = o4;
        }
    }
}

extern "C" void kernel_launch(void* const* d_in, const int* in_sizes, int n_in,
                              void* d_out, int out_size, void* d_ws, size_t ws_size,
                              hipStream_t stream) {
    (void)in_sizes; (void)n_in; (void)out_size; (void)d_ws; (void)ws_size;
    const float* x        = (const float*)d_in[0];
    const float* w_offset = (const float*)d_in[1];
    const float* b_offset = (const float*)d_in[2];
    const float* w_mask   = (const float*)d_in[3];
    const float* b_mask   = (const float*)d_in[4];
    const float* w_conv   = (const float*)d_in[5];
    const float* bn_gamma = (const float*)d_in[6];
    const float* bn_beta  = (const float*)d_in[7];
    const float* bn_mean  = (const float*)d_in[8];
    const float* bn_var   = (const float*)d_in[9];
    float* out = (float*)d_out;

    int prep_elems = 32 * KTOT + OUTC * KTOT;
    prep_kernel<<<(prep_elems + 255) / 256, 256, 0, stream>>>(w_offset, w_mask, w_conv);
    fused_kernel<<<BB * HH * 2, 512, 0, stream>>>(x, b_offset, b_mask,
                                                  bn_gamma, bn_beta, bn_mean, bn_var, out);
}

// Round 23
// 81.095 us; speedup vs baseline: 1.6432x; 1.6432x over previous
//
#include <hip/hip_runtime.h>
#include <math.h>

#define BB 8
#define CC 128
#define HH 64
#define WW 64
#define NPTS 9
#define OUTC 256
#define HW (HH*WW)
#define KTOT (CC*NPTS)   // 1152
#define BK 288           // 32 channels * 9 taps per K-chunk
#define AP 290           // Atile row in bf16 elems: 580 B = 145 words (ODD -> 2-way=free)
#define WROWS 6          // x row window: global rows h-2 .. h+3

typedef __attribute__((ext_vector_type(8))) short bf16x8;
typedef __attribute__((ext_vector_type(4))) float f32x4;

// bf16 weights, k-order permuted: k = cb*288 + pair*18 + n*2 + half,
// where channel c = cb*32 + pair*2 + half, tap n = ky*3+kx.
__device__ unsigned short g_wT[OUTC * KTOT];   // main conv weights
__device__ unsigned short g_woT[32 * KTOT];    // offset(18)+mask(9)+zero(5)

__device__ __forceinline__ unsigned short f2bf(float f) {
    unsigned int u = __builtin_bit_cast(unsigned int, f);
    unsigned int r = (u + 0x7FFFu + ((u >> 16) & 1u)) >> 16;   // RNE
    return (unsigned short)r;
}

__device__ __forceinline__ unsigned cvtpk(float lo, float hi) {   // {bf16(lo), bf16(hi)<<16}
    unsigned r;
    asm("v_cvt_pk_bf16_f32 %0, %1, %2" : "=v"(r) : "v"(lo), "v"(hi));
    return r;
}
__device__ __forceinline__ float bflo(unsigned w) { return __builtin_bit_cast(float, w << 16); }
__device__ __forceinline__ float bfhi(unsigned w) { return __builtin_bit_cast(float, w & 0xFFFF0000u); }

__device__ __forceinline__ int orig_k(int k) {      // permuted k -> original c*9+n
    int cb = k / BK, r = k % BK;
    int pair = r / 18, r2 = r % 18;
    int n = r2 >> 1, half = r2 & 1;
    return (cb * 32 + pair * 2 + half) * NPTS + n;
}

__global__ __launch_bounds__(256) void prep_kernel(
    const float* __restrict__ wo, const float* __restrict__ wm,
    const float* __restrict__ wc)
{
    int idx = blockIdx.x * 256 + threadIdx.x;
    const int T1 = 32 * KTOT;
    if (idx < T1) {
        int nn = idx / KTOT, k = idx - nn * KTOT;
        int ok = orig_k(k);
        float v = (nn < 18) ? wo[nn * KTOT + ok]
                            : (nn < 27 ? wm[(nn - 18) * KTOT + ok] : 0.f);
        g_woT[idx] = f2bf(v);
    } else if (idx < T1 + OUTC * KTOT) {
        int j = idx - T1;
        int oc = j / KTOT, k = j - oc * KTOT;
        g_wT[j] = f2bf(wc[oc * KTOT + orig_k(k)]);
    }
}

// Quad staging (R12-proven): wave w stages AND consumes quad w -> the window
// is wave-private, no barriers around commit/build. PF = 6 uint2 = 12 VGPRs.
struct PF { uint2 w[WROWS]; };

__device__ __forceinline__ void issue(PF& pf, const float* __restrict__ xb,
                                      int h, int cb, int tid) {
    if (cb < 0 || cb > 3) return;
    int q = tid >> 6, col = tid & 63;         // q = wave id
    const float* base = xb + (size_t)(cb * 32 + 4 * q) * HW + col;
    #pragma unroll
    for (int r = 0; r < WROWS; ++r) {
        int gr = h - 2 + r;
        bool v = (gr >= 0) & (gr < HH);
        float a0 = v ? base[0 * HW + gr * WW] : 0.f;
        float a1 = v ? base[1 * HW + gr * WW] : 0.f;
        float a2 = v ? base[2 * HW + gr * WW] : 0.f;
        float a3 = v ? base[3 * HW + gr * WW] : 0.f;
        pf.w[r].x = cvtpk(a0, a1);
        pf.w[r].y = cvtpk(a2, a3);
    }
}

__device__ __forceinline__ void commit(uint2* win, const PF& pf, int tid) {
    uint2* wp = win + (tid >> 6) * 384 + (tid & 63);
    #pragma unroll
    for (int r = 0; r < WROWS; ++r) wp[r * 64] = pf.w[r];   // ds_write_b64
}

// 512 threads = 8 waves; LDS 73.8 KB -> 2 blocks/CU. Structure lattice
// (all measured): 2 blocks/CU mandatory (R14); no duplicated build (R13/R16);
// coarse 32-ch phases (R17); no duplicated STAGING either (R22: 133us).
// This is the verified best: R18 + wave-parallel param stage (R21, 81.5us).
__global__ __launch_bounds__(512) __attribute__((amdgpu_waves_per_eu(4, 4)))
void fused_kernel(
    const float* __restrict__ x,
    const float* __restrict__ b_offset, const float* __restrict__ b_mask,
    const float* __restrict__ bn_gamma, const float* __restrict__ bn_beta,
    const float* __restrict__ bn_mean,  const float* __restrict__ bn_var,
    float* __restrict__ out)
{
    __shared__ unsigned short Atile[64][AP];     // 37120 B
    __shared__ uint2 win[8 * 384];               // 24576 B quad-packed bf16 window
    __shared__ float4 gtab[NPTS][64];            //  9216 B bilinear weights (b128/lane)
    __shared__ uint2  otab[NPTS][64];            //  4608 B 4 x u16 offsets (b64/lane)
    // px/py/m overlay lives in ATILE (dead between pass-A MFMA and pass-B
    // build) so the staged window survives the A->B transition (cb3 resident).
    float* ovf = (float*)&Atile[0][0];           // 6912 B used

    // T1 XCD-chunked swizzle (R12-proven: FETCH 99 -> 11 MB).
    int bid = blockIdx.x;
    int blk = (bid & 7) * 64 + (bid >> 3);
    int b = blk >> 6, h = blk & 63;
    int tid  = threadIdx.x;
    int lane = tid & 63;
    int wv   = __builtin_amdgcn_readfirstlane(tid >> 6);  // wave 0..7
    int l15  = lane & 15;
    int kg   = lane >> 4;
    int spix = lane;

    const float* xb = x + (size_t)b * CC * HW;
    unsigned* AtU = (unsigned*)&Atile[0][0];     // row stride 145 uints (odd -> spread)

    // ================= PASS A: offset/mask conv (M=64,N=32,K=1152) =========
    int mi_a = wv & 3, nf_a = wv >> 2;
    f32x4 s1acc = {0.f, 0.f, 0.f, 0.f};

    PF pf; issue(pf, xb, h, 0, tid);
    for (int cb = 0; cb < 4; ++cb) {
        commit(win, pf, tid);                // wave-private: no barrier needed
        {
            const uint2* base = win + wv * 384;
            #pragma unroll
            for (int tap = 0; tap < 9; ++tap) {
                int ky = tap / 3, kx = tap % 3;
                int col  = spix + kx - 1;
                int colc = min(max(col, 0), WW - 1);
                uint2 v = base[(ky + 1) * 64 + colc];
                bool cv = (col >= 0) & (col < WW);
                AtU[spix * 145 + (2 * wv) * 9 + tap]     = cv ? v.x : 0u;
                AtU[spix * 145 + (2 * wv + 1) * 9 + tap] = cv ? v.y : 0u;
            }
        }
        // prefetch: cb+1 for cb<3; at cb==3 prefetch cb2 (pass B runs 3,2,1,0
        // and phase 3 uses the RESIDENT window - no staging needed for it).
        issue(pf, xb, h, (cb < 3) ? cb + 1 : 2, tid);
        __syncthreads();                     // Atile complete
        __builtin_amdgcn_s_setprio(1);
        for (int q = 0; q < 9; ++q) {
            int koff = q * 32 + kg * 8;
            bf16x8 af = *(const bf16x8*)&Atile[mi_a * 16 + l15][koff];
            int nn = nf_a * 16 + l15;
            bf16x8 bfr = *(const bf16x8*)&g_woT[nn * KTOT + cb * BK + koff];
            s1acc = __builtin_amdgcn_mfma_f32_16x16x32_bf16(af, bfr, s1acc, 0, 0, 0);
        }
        __builtin_amdgcn_s_setprio(0);
        __syncthreads();                     // MFMA done; next build may overwrite
    }

    // ---- pass-A epilogue into Atile overlay (Atile dead; win kept!) --------
    #pragma unroll
    for (int j = 0; j < 4; ++j) {
        float val = s1acc[j];
        int nn   = nf_a * 16 + l15;
        int pixl = mi_a * 16 + kg * 4 + j;
        if (nn < 9) {
            ovf[nn * 64 + pixl] = val + b_offset[nn] + (float)(nn / 3 - 1) + (float)(h + 1);
        } else if (nn < 18) {
            int n = nn - 9;
            ovf[576 + n * 64 + pixl] = val + b_offset[nn] + (float)(n % 3 - 1) + (float)(pixl + 1);
        } else if (nn < 27) {
            int n = nn - 18;
            float sg = val + b_mask[n];
            ovf[1152 + n * 64 + pixl] = 1.f / (1.f + expf(-sg));
        }
    }
    __syncthreads();

    // ================= param tables: WAVE-PARALLEL (n = wv; wave0 also n=8) =
    // otab[n][t] = 4 x u16 FINAL offsets {o00, o11, o01, o10}; bit15 of the
    // o00 slot = global-fallback flag. Same algebra both paths -> exact.
    for (int n = wv; n < NPTS; n += 8) {
        int t = lane;
        float px = ovf[n * 64 + t];
        float py = ovf[576 + n * 64 + t];
        float m  = ovf[1152 + n * 64 + t];
        float fx = floorf(px), fy = floorf(py);
        float qltx = fminf(fmaxf(fx,       0.f), 65.f);
        float qlty = fminf(fmaxf(fy,       0.f), 65.f);
        float qrbx = fminf(fmaxf(fx + 1.f, 0.f), 65.f);
        float qrby = fminf(fmaxf(fy + 1.f, 0.f), 65.f);
        float pxc  = fminf(fmaxf(px, 0.f), 65.f);
        float pyc  = fminf(fmaxf(py, 0.f), 65.f);
        float glt = (1.f + (qltx - pxc)) * (1.f + (qlty - pyc)) * m;
        float grb = (1.f - (qrbx - pxc)) * (1.f - (qrby - pyc)) * m;
        float glb = (1.f + (qltx - pxc)) * (1.f - (qrby - pyc)) * m;
        float grt = (1.f - (qrbx - pxc)) * (1.f + (qlty - pyc)) * m;
        int i0 = (int)qltx - 1, j0 = (int)qlty - 1;
        int i1 = (int)qrbx - 1, j1 = (int)qrby - 1;
        bool v00 = (i0 >= 0) & (i0 < HH) & (j0 >= 0) & (j0 < WW);
        bool v11 = (i1 >= 0) & (i1 < HH) & (j1 >= 0) & (j1 < WW);
        bool v01 = (i0 >= 0) & (i0 < HH) & (j1 >= 0) & (j1 < WW);
        bool v10 = (i1 >= 0) & (i1 < HH) & (j0 >= 0) & (j0 < WW);
        float4 g;
        g.x = v00 ? glt : 0.f;   // (i0,j0)
        g.y = v11 ? grb : 0.f;   // (i1,j1)
        g.z = v01 ? glb : 0.f;   // (i0,j1)
        g.w = v10 ? grt : 0.f;   // (i1,j0)
        gtab[n][t] = g;
        bool okr0 = ((i0 >= h - 2) & (i0 <= h + 3)) | !(v00 | v01);
        bool okr1 = ((i1 >= h - 2) & (i1 <= h + 3)) | !(v11 | v10);
        bool ok = okr0 & okr1;
        int r0w = min(max(i0 - (h - 2), 0), WROWS - 1);
        int r1w = min(max(i1 - (h - 2), 0), WROWS - 1);
        int r0g = min(max(i0, 0), HH - 1);
        int r1g = min(max(i1, 0), HH - 1);
        int j0c = min(max(j0, 0), WW - 1);
        int j1c = min(max(j1, 0), WW - 1);
        int o  = ok ? (r0w * WW + j0c) : (r0g * WW + j0c);
        int dr = ok ? (r1w - r0w) : (r1g - r0g);
        int dj = j1c - j0c;
        unsigned o00 = (unsigned)o;
        unsigned o11 = (unsigned)(o + dr * WW + dj);
        unsigned o01 = (unsigned)(o + dj);
        unsigned o10 = (unsigned)(o + dr * WW);
        uint2 ot;
        ot.x = (o00 | (ok ? 0u : 0x8000u)) | (o11 << 16);
        ot.y = o01 | (o10 << 16);
        otab[n][t] = ot;
    }
    __syncthreads();                         // params ready; ovf (in Atile) dead

    // ================= PASS B: main GEMM, K order 3,2,1,0 ===================
    // Phase 3 builds from the window left resident by pass A (no staging);
    // pf holds cb2 (issued during pass A's last phase).
    f32x4 acc[4][2];
    #pragma unroll
    for (int mi = 0; mi < 4; ++mi)
        #pragma unroll
        for (int ni = 0; ni < 2; ++ni)
            acc[mi][ni] = (f32x4){0.f, 0.f, 0.f, 0.f};

    int oc0 = wv * 32;

    for (int j = 0; j < 4; ++j) {
        int cb = 3 - j;                      // chunk built + consumed this phase
        if (j > 0) {
            commit(win, pf, tid);            // window for this cb (wave-private)
            issue(pf, xb, h, cb - 1, tid);   // prefetch next (cb-1; guard skips -1)
        }
        {
            const uint2* baseq = win + wv * 384;
            const float* xg = xb + (size_t)(cb * 32 + 4 * wv) * HW;
            #pragma unroll
            for (int n = 0; n < NPTS; ++n) {
                float4 g  = gtab[n][spix];   // one ds_read_b128
                uint2  ot = otab[n][spix];   // one ds_read_b64
                int o00 = ot.x & 0x7FFF;
                int o11 = ot.x >> 16;
                int o01 = ot.y & 0xFFFF;
                int o10 = ot.y >> 16;
                float v0, v1, v2, v3;
                if (!(ot.x & 0x8000u)) {     // in-window: quad bf16 b64 reads
                    uint2 c00 = baseq[o00];
                    uint2 c11 = baseq[o11];
                    uint2 c01 = baseq[o01];
                    uint2 c10 = baseq[o10];
                    v0 =       g.x * bflo(c00.x);
                    v0 = fmaf(g.y, bflo(c11.x), v0);
                    v0 = fmaf(g.z, bflo(c01.x), v0);
                    v0 = fmaf(g.w, bflo(c10.x), v0);
                    v1 =       g.x * bfhi(c00.x);
                    v1 = fmaf(g.y, bfhi(c11.x), v1);
                    v1 = fmaf(g.z, bfhi(c01.x), v1);
                    v1 = fmaf(g.w, bfhi(c10.x), v1);
                    v2 =       g.x * bflo(c00.y);
                    v2 = fmaf(g.y, bflo(c11.y), v2);
                    v2 = fmaf(g.z, bflo(c01.y), v2);
                    v2 = fmaf(g.w, bflo(c10.y), v2);
                    v3 =       g.x * bfhi(c00.y);
                    v3 = fmaf(g.y, bfhi(c11.y), v3);
                    v3 = fmaf(g.z, bfhi(c01.y), v3);
                    v3 = fmaf(g.w, bfhi(c10.y), v3);
                } else {                     // rare: f32 global corners, 4 ch
                    const float* x0 = xg;
                    const float* x1 = xg + HW;
                    const float* x2 = xg + 2 * HW;
                    const float* x3 = xg + 3 * HW;
                    v0 = g.x*x0[o00]; v0 = fmaf(g.y, x0[o11], v0); v0 = fmaf(g.z, x0[o01], v0); v0 = fmaf(g.w, x0[o10], v0);
                    v1 = g.x*x1[o00]; v1 = fmaf(g.y, x1[o11], v1); v1 = fmaf(g.z, x1[o01], v1); v1 = fmaf(g.w, x1[o10], v1);
                    v2 = g.x*x2[o00]; v2 = fmaf(g.y, x2[o11], v2); v2 = fmaf(g.z, x2[o01], v2); v2 = fmaf(g.w, x2[o10], v2);
                    v3 = g.x*x3[o00]; v3 = fmaf(g.y, x3[o11], v3); v3 = fmaf(g.z, x3[o01], v3); v3 = fmaf(g.w, x3[o10], v3);
                }
                AtU[spix * 145 + (2 * wv) * 9 + n]     = cvtpk(v0, v1);
                AtU[spix * 145 + (2 * wv + 1) * 9 + n] = cvtpk(v2, v3);
            }
        }
        __syncthreads();                     // Atile complete
        __builtin_amdgcn_s_setprio(1);
        for (int q = 0; q < 9; ++q) {
            int koff = q * 32 + kg * 8;
            bf16x8 af[4];
            #pragma unroll
            for (int mi = 0; mi < 4; ++mi)
                af[mi] = *(const bf16x8*)&Atile[mi * 16 + l15][koff];
            #pragma unroll
            for (int ni = 0; ni < 2; ++ni) {
                int oc = oc0 + ni * 16 + l15;
                bf16x8 bfr = *(const bf16x8*)&g_wT[oc * KTOT + cb * BK + koff];
                #pragma unroll
                for (int mi = 0; mi < 4; ++mi)
                    acc[mi][ni] = __builtin_amdgcn_mfma_f32_16x16x32_bf16(af[mi], bfr, acc[mi][ni], 0, 0, 0);
            }
        }
        __builtin_amdgcn_s_setprio(0);
        __syncthreads();                     // MFMA done; next build may overwrite
    }

    // ================= epilogue: BN + ReLU, float4 stores ===================
    #pragma unroll
    for (int ni = 0; ni < 2; ++ni) {
        int oc = oc0 + ni * 16 + l15;
        float inv   = 1.f / sqrtf(bn_var[oc] + 1e-5f);
        float scale = bn_gamma[oc] * inv;
        float shift = bn_beta[oc] - bn_mean[oc] * scale;
        float* op = out + ((size_t)b * OUTC + oc) * HW + h * WW + kg * 4;
        #pragma unroll
        for (int mi = 0; mi < 4; ++mi) {
            f32x4 o4;
            #pragma unroll
            for (int j = 0; j < 4; ++j) {
                float v = fmaf(acc[mi][ni][j], scale, shift);
                o4[j] = v > 0.f ? v : 0.f;
            }
            *(f32x4*)(op + mi * 16) = o4;
        }
    }
}

extern "C" void kernel_launch(void* const* d_in, const int* in_sizes, int n_in,
                              void* d_out, int out_size, void* d_ws, size_t ws_size,
                              hipStream_t stream) {
    (void)in_sizes; (void)n_in; (void)out_size; (void)d_ws; (void)ws_size;
    const float* x        = (const float*)d_in[0];
    const float* w_offset = (const float*)d_in[1];
    const float* b_offset = (const float*)d_in[2];
    const float* w_mask   = (const float*)d_in[3];
    const float* b_mask   = (const float*)d_in[4];
    const float* w_conv   = (const float*)d_in[5];
    const float* bn_gamma = (const float*)d_in[6];
    const float* bn_beta  = (const float*)d_in[7];
    const float* bn_mean  = (const float*)d_in[8];
    const float* bn_var   = (const float*)d_in[9];
    float* out = (float*)d_out;

    int prep_elems = 32 * KTOT + OUTC * KTOT;
    prep_kernel<<<(prep_elems + 255) / 256, 256, 0, stream>>>(w_offset, w_mask, w_conv);
    fused_kernel<<<BB * HH, 512, 0, stream>>>(x, b_offset, b_mask,
                                              bn_gamma, bn_beta, bn_mean, bn_var, out);
}

// Round 24
// 78.911 us; speedup vs baseline: 1.6886x; 1.0277x over previous
//
#include <hip/hip_runtime.h>
#include <math.h>

#define BB 8
#define CC 128
#define HH 64
#define WW 64
#define NPTS 9
#define OUTC 256
#define HW (HH*WW)
#define KTOT (CC*NPTS)   // 1152
#define BK 288           // 32 channels * 9 taps per K-chunk
#define AP 290           // Atile row in bf16 elems: 580 B = 145 words (ODD -> 2-way=free)
#define WROWS 6          // x row window: global rows h-2 .. h+3

typedef __attribute__((ext_vector_type(8))) short bf16x8;
typedef __attribute__((ext_vector_type(4))) float f32x4;

// bf16 weights, k-order permuted: k = cb*288 + pair*18 + n*2 + half,
// where channel c = cb*32 + pair*2 + half, tap n = ky*3+kx.
__device__ unsigned short g_wT[OUTC * KTOT];   // main conv weights
__device__ unsigned short g_woT[32 * KTOT];    // offset(18)+mask(9)+zero(5)

__device__ __forceinline__ unsigned short f2bf(float f) {
    unsigned int u = __builtin_bit_cast(unsigned int, f);
    unsigned int r = (u + 0x7FFFu + ((u >> 16) & 1u)) >> 16;   // RNE
    return (unsigned short)r;
}

__device__ __forceinline__ unsigned cvtpk(float lo, float hi) {   // {bf16(lo), bf16(hi)<<16}
    unsigned r;
    asm("v_cvt_pk_bf16_f32 %0, %1, %2" : "=v"(r) : "v"(lo), "v"(hi));
    return r;
}
__device__ __forceinline__ float bflo(unsigned w) { return __builtin_bit_cast(float, w << 16); }
__device__ __forceinline__ float bfhi(unsigned w) { return __builtin_bit_cast(float, w & 0xFFFF0000u); }

__device__ __forceinline__ int orig_k(int k) {      // permuted k -> original c*9+n
    int cb = k / BK, r = k % BK;
    int pair = r / 18, r2 = r % 18;
    int n = r2 >> 1, half = r2 & 1;
    return (cb * 32 + pair * 2 + half) * NPTS + n;
}

__global__ __launch_bounds__(256) void prep_kernel(
    const float* __restrict__ wo, const float* __restrict__ wm,
    const float* __restrict__ wc)
{
    int idx = blockIdx.x * 256 + threadIdx.x;
    const int T1 = 32 * KTOT;
    if (idx < T1) {
        int nn = idx / KTOT, k = idx - nn * KTOT;
        int ok = orig_k(k);
        float v = (nn < 18) ? wo[nn * KTOT + ok]
                            : (nn < 27 ? wm[(nn - 18) * KTOT + ok] : 0.f);
        g_woT[idx] = f2bf(v);
    } else if (idx < T1 + OUTC * KTOT) {
        int j = idx - T1;
        int oc = j / KTOT, k = j - oc * KTOT;
        g_wT[j] = f2bf(wc[oc * KTOT + orig_k(k)]);
    }
}

// Quad staging (R12-proven): wave w stages AND consumes quad w -> the window
// is wave-private, no barriers around commit/build. PF = 6 uint2 = 12 VGPRs.
struct PF { uint2 w[WROWS]; };

__device__ __forceinline__ void issue(PF& pf, const float* __restrict__ xb,
                                      int h, int cb, int tid) {
    if (cb < 0 || cb > 3) return;
    int q = tid >> 6, col = tid & 63;         // q = wave id
    const float* base = xb + (size_t)(cb * 32 + 4 * q) * HW + col;
    #pragma unroll
    for (int r = 0; r < WROWS; ++r) {
        int gr = h - 2 + r;
        bool v = (gr >= 0) & (gr < HH);
        float a0 = v ? base[0 * HW + gr * WW] : 0.f;
        float a1 = v ? base[1 * HW + gr * WW] : 0.f;
        float a2 = v ? base[2 * HW + gr * WW] : 0.f;
        float a3 = v ? base[3 * HW + gr * WW] : 0.f;
        pf.w[r].x = cvtpk(a0, a1);
        pf.w[r].y = cvtpk(a2, a3);
    }
}

__device__ __forceinline__ void commit(uint2* win, const PF& pf, int tid) {
    uint2* wp = win + (tid >> 6) * 384 + (tid & 63);
    #pragma unroll
    for (int r = 0; r < WROWS; ++r) wp[r * 64] = pf.w[r];   // ds_write_b64
}

// 512 threads = 8 waves; LDS 73.8 KB -> 2 blocks/CU. Structure lattice
// (all measured): 2 blocks/CU mandatory (R14); no duplicated build (R13/R16);
// coarse 32-ch phases (R17); no duplicated staging (R22). This is R21
// (verified best, 81.1-81.5us) + weight-fragment register prefetch: the
// q<4 MFMA B-operands are Atile-independent, so issue their L2 loads
// BEFORE the barrier. waves_per_eu(4,4) pins the VGPR tier at 128
// (occupancy is LDS-limited), so +48 prefetch regs stay spill-free.
__global__ __launch_bounds__(512) __attribute__((amdgpu_waves_per_eu(4, 4)))
void fused_kernel(
    const float* __restrict__ x,
    const float* __restrict__ b_offset, const float* __restrict__ b_mask,
    const float* __restrict__ bn_gamma, const float* __restrict__ bn_beta,
    const float* __restrict__ bn_mean,  const float* __restrict__ bn_var,
    float* __restrict__ out)
{
    __shared__ unsigned short Atile[64][AP];     // 37120 B
    __shared__ uint2 win[8 * 384];               // 24576 B quad-packed bf16 window
    __shared__ float4 gtab[NPTS][64];            //  9216 B bilinear weights (b128/lane)
    __shared__ uint2  otab[NPTS][64];            //  4608 B 4 x u16 offsets (b64/lane)
    // px/py/m overlay lives in ATILE (dead between pass-A MFMA and pass-B
    // build) so the staged window survives the A->B transition (cb3 resident).
    float* ovf = (float*)&Atile[0][0];           // 6912 B used

    // T1 XCD-chunked swizzle (R12-proven: FETCH 99 -> 11 MB).
    int bid = blockIdx.x;
    int blk = (bid & 7) * 64 + (bid >> 3);
    int b = blk >> 6, h = blk & 63;
    int tid  = threadIdx.x;
    int lane = tid & 63;
    int wv   = __builtin_amdgcn_readfirstlane(tid >> 6);  // wave 0..7
    int l15  = lane & 15;
    int kg   = lane >> 4;
    int spix = lane;

    const float* xb = x + (size_t)b * CC * HW;
    unsigned* AtU = (unsigned*)&Atile[0][0];     // row stride 145 uints (odd -> spread)

    // ================= PASS A: offset/mask conv (M=64,N=32,K=1152) =========
    int mi_a = wv & 3, nf_a = wv >> 2;
    f32x4 s1acc = {0.f, 0.f, 0.f, 0.f};

    PF pf; issue(pf, xb, h, 0, tid);
    for (int cb = 0; cb < 4; ++cb) {
        commit(win, pf, tid);                // wave-private: no barrier needed
        {
            const uint2* base = win + wv * 384;
            #pragma unroll
            for (int tap = 0; tap < 9; ++tap) {
                int ky = tap / 3, kx = tap % 3;
                int col  = spix + kx - 1;
                int colc = min(max(col, 0), WW - 1);
                uint2 v = base[(ky + 1) * 64 + colc];
                bool cv = (col >= 0) & (col < WW);
                AtU[spix * 145 + (2 * wv) * 9 + tap]     = cv ? v.x : 0u;
                AtU[spix * 145 + (2 * wv + 1) * 9 + tap] = cv ? v.y : 0u;
            }
        }
        // prefetch: cb+1 for cb<3; at cb==3 prefetch cb2 (pass B runs 3,2,1,0
        // and phase 3 uses the RESIDENT window - no staging needed for it).
        issue(pf, xb, h, (cb < 3) ? cb + 1 : 2, tid);
        // weight prefetch for q=0..3 (Atile-independent -> hide L2 latency
        // under the barrier). 16 VGPRs.
        int nn_a = nf_a * 16 + l15;
        bf16x8 wpa[4];
        #pragma unroll
        for (int q = 0; q < 4; ++q)
            wpa[q] = *(const bf16x8*)&g_woT[nn_a * KTOT + cb * BK + q * 32 + kg * 8];
        __syncthreads();                     // Atile complete
        __builtin_amdgcn_s_setprio(1);
        for (int q = 0; q < 9; ++q) {
            int koff = q * 32 + kg * 8;
            bf16x8 af = *(const bf16x8*)&Atile[mi_a * 16 + l15][koff];
            bf16x8 bfr = (q < 4) ? wpa[q]
                : *(const bf16x8*)&g_woT[nn_a * KTOT + cb * BK + koff];
            s1acc = __builtin_amdgcn_mfma_f32_16x16x32_bf16(af, bfr, s1acc, 0, 0, 0);
        }
        __builtin_amdgcn_s_setprio(0);
        __syncthreads();                     // MFMA done; next build may overwrite
    }

    // ---- pass-A epilogue into Atile overlay (Atile dead; win kept!) --------
    #pragma unroll
    for (int j = 0; j < 4; ++j) {
        float val = s1acc[j];
        int nn   = nf_a * 16 + l15;
        int pixl = mi_a * 16 + kg * 4 + j;
        if (nn < 9) {
            ovf[nn * 64 + pixl] = val + b_offset[nn] + (float)(nn / 3 - 1) + (float)(h + 1);
        } else if (nn < 18) {
            int n = nn - 9;
            ovf[576 + n * 64 + pixl] = val + b_offset[nn] + (float)(n % 3 - 1) + (float)(pixl + 1);
        } else if (nn < 27) {
            int n = nn - 18;
            float sg = val + b_mask[n];
            ovf[1152 + n * 64 + pixl] = 1.f / (1.f + expf(-sg));
        }
    }
    __syncthreads();

    // ================= param tables: WAVE-PARALLEL (n = wv; wave0 also n=8) =
    // otab[n][t] = 4 x u16 FINAL offsets {o00, o11, o01, o10}; bit15 of the
    // o00 slot = global-fallback flag. Same algebra both paths -> exact.
    for (int n = wv; n < NPTS; n += 8) {
        int t = lane;
        float px = ovf[n * 64 + t];
        float py = ovf[576 + n * 64 + t];
        float m  = ovf[1152 + n * 64 + t];
        float fx = floorf(px), fy = floorf(py);
        float qltx = fminf(fmaxf(fx,       0.f), 65.f);
        float qlty = fminf(fmaxf(fy,       0.f), 65.f);
        float qrbx = fminf(fmaxf(fx + 1.f, 0.f), 65.f);
        float qrby = fminf(fmaxf(fy + 1.f, 0.f), 65.f);
        float pxc  = fminf(fmaxf(px, 0.f), 65.f);
        float pyc  = fminf(fmaxf(py, 0.f), 65.f);
        float glt = (1.f + (qltx - pxc)) * (1.f + (qlty - pyc)) * m;
        float grb = (1.f - (qrbx - pxc)) * (1.f - (qrby - pyc)) * m;
        float glb = (1.f + (qltx - pxc)) * (1.f - (qrby - pyc)) * m;
        float grt = (1.f - (qrbx - pxc)) * (1.f + (qlty - pyc)) * m;
        int i0 = (int)qltx - 1, j0 = (int)qlty - 1;
        int i1 = (int)qrbx - 1, j1 = (int)qrby - 1;
        bool v00 = (i0 >= 0) & (i0 < HH) & (j0 >= 0) & (j0 < WW);
        bool v11 = (i1 >= 0) & (i1 < HH) & (j1 >= 0) & (j1 < WW);
        bool v01 = (i0 >= 0) & (i0 < HH) & (j1 >= 0) & (j1 < WW);
        bool v10 = (i1 >= 0) & (i1 < HH) & (j0 >= 0) & (j0 < WW);
        float4 g;
        g.x = v00 ? glt : 0.f;   // (i0,j0)
        g.y = v11 ? grb : 0.f;   // (i1,j1)
        g.z = v01 ? glb : 0.f;   // (i0,j1)
        g.w = v10 ? grt : 0.f;   // (i1,j0)
        gtab[n][t] = g;
        bool okr0 = ((i0 >= h - 2) & (i0 <= h + 3)) | !(v00 | v01);
        bool okr1 = ((i1 >= h - 2) & (i1 <= h + 3)) | !(v11 | v10);
        bool ok = okr0 & okr1;
        int r0w = min(max(i0 - (h - 2), 0), WROWS - 1);
        int r1w = min(max(i1 - (h - 2), 0), WROWS - 1);
        int r0g = min(max(i0, 0), HH - 1);
        int r1g = min(max(i1, 0), HH - 1);
        int j0c = min(max(j0, 0), WW - 1);
        int j1c = min(max(j1, 0), WW - 1);
        int o  = ok ? (r0w * WW + j0c) : (r0g * WW + j0c);
        int dr = ok ? (r1w - r0w) : (r1g - r0g);
        int dj = j1c - j0c;
        unsigned o00 = (unsigned)o;
        unsigned o11 = (unsigned)(o + dr * WW + dj);
        unsigned o01 = (unsigned)(o + dj);
        unsigned o10 = (unsigned)(o + dr * WW);
        uint2 ot;
        ot.x = (o00 | (ok ? 0u : 0x8000u)) | (o11 << 16);
        ot.y = o01 | (o10 << 16);
        otab[n][t] = ot;
    }
    __syncthreads();                         // params ready; ovf (in Atile) dead

    // ================= PASS B: main GEMM, K order 3,2,1,0 ===================
    // Phase 3 builds from the window left resident by pass A (no staging);
    // pf holds cb2 (issued during pass A's last phase).
    f32x4 acc[4][2];
    #pragma unroll
    for (int mi = 0; mi < 4; ++mi)
        #pragma unroll
        for (int ni = 0; ni < 2; ++ni)
            acc[mi][ni] = (f32x4){0.f, 0.f, 0.f, 0.f};

    int oc0 = wv * 32;

    for (int j = 0; j < 4; ++j) {
        int cb = 3 - j;                      // chunk built + consumed this phase
        if (j > 0) {
            commit(win, pf, tid);            // window for this cb (wave-private)
            issue(pf, xb, h, cb - 1, tid);   // prefetch next (cb-1; guard skips -1)
        }
        {
            const uint2* baseq = win + wv * 384;
            const float* xg = xb + (size_t)(cb * 32 + 4 * wv) * HW;
            #pragma unroll
            for (int n = 0; n < NPTS; ++n) {
                float4 g  = gtab[n][spix];   // one ds_read_b128
                uint2  ot = otab[n][spix];   // one ds_read_b64
                int o00 = ot.x & 0x7FFF;
                int o11 = ot.x >> 16;
                int o01 = ot.y & 0xFFFF;
                int o10 = ot.y >> 16;
                float v0, v1, v2, v3;
                if (!(ot.x & 0x8000u)) {     // in-window: quad bf16 b64 reads
                    uint2 c00 = baseq[o00];
                    uint2 c11 = baseq[o11];
                    uint2 c01 = baseq[o01];
                    uint2 c10 = baseq[o10];
                    v0 =       g.x * bflo(c00.x);
                    v0 = fmaf(g.y, bflo(c11.x), v0);
                    v0 = fmaf(g.z, bflo(c01.x), v0);
                    v0 = fmaf(g.w, bflo(c10.x), v0);
                    v1 =       g.x * bfhi(c00.x);
                    v1 = fmaf(g.y, bfhi(c11.x), v1);
                    v1 = fmaf(g.z, bfhi(c01.x), v1);
                    v1 = fmaf(g.w, bfhi(c10.x), v1);
                    v2 =       g.x * bflo(c00.y);
                    v2 = fmaf(g.y, bflo(c11.y), v2);
                    v2 = fmaf(g.z, bflo(c01.y), v2);
                    v2 = fmaf(g.w, bflo(c10.y), v2);
                    v3 =       g.x * bfhi(c00.y);
                    v3 = fmaf(g.y, bfhi(c11.y), v3);
                    v3 = fmaf(g.z, bfhi(c01.y), v3);
                    v3 = fmaf(g.w, bfhi(c10.y), v3);
                } else {                     // rare: f32 global corners, 4 ch
                    const float* x0 = xg;
                    const float* x1 = xg + HW;
                    const float* x2 = xg + 2 * HW;
                    const float* x3 = xg + 3 * HW;
                    v0 = g.x*x0[o00]; v0 = fmaf(g.y, x0[o11], v0); v0 = fmaf(g.z, x0[o01], v0); v0 = fmaf(g.w, x0[o10], v0);
                    v1 = g.x*x1[o00]; v1 = fmaf(g.y, x1[o11], v1); v1 = fmaf(g.z, x1[o01], v1); v1 = fmaf(g.w, x1[o10], v1);
                    v2 = g.x*x2[o00]; v2 = fmaf(g.y, x2[o11], v2); v2 = fmaf(g.z, x2[o01], v2); v2 = fmaf(g.w, x2[o10], v2);
                    v3 = g.x*x3[o00]; v3 = fmaf(g.y, x3[o11], v3); v3 = fmaf(g.z, x3[o01], v3); v3 = fmaf(g.w, x3[o10], v3);
                }
                AtU[spix * 145 + (2 * wv) * 9 + n]     = cvtpk(v0, v1);
                AtU[spix * 145 + (2 * wv + 1) * 9 + n] = cvtpk(v2, v3);
            }
        }
        // weight prefetch for q=0..3, both ni (Atile-independent -> issue
        // before the barrier; L2 latency hides under barrier wait). 32 VGPRs.
        bf16x8 wpb[2][4];
        #pragma unroll
        for (int ni = 0; ni < 2; ++ni) {
            int oc = oc0 + ni * 16 + l15;
            #pragma unroll
            for (int q = 0; q < 4; ++q)
                wpb[ni][q] = *(const bf16x8*)&g_wT[oc * KTOT + cb * BK + q * 32 + kg * 8];
        }
        __syncthreads();                     // Atile complete
        __builtin_amdgcn_s_setprio(1);
        for (int q = 0; q < 9; ++q) {
            int koff = q * 32 + kg * 8;
            bf16x8 af[4];
            #pragma unroll
            for (int mi = 0; mi < 4; ++mi)
                af[mi] = *(const bf16x8*)&Atile[mi * 16 + l15][koff];
            #pragma unroll
            for (int ni = 0; ni < 2; ++ni) {
                int oc = oc0 + ni * 16 + l15;
                bf16x8 bfr = (q < 4) ? wpb[ni][q]
                    : *(const bf16x8*)&g_wT[oc * KTOT + cb * BK + koff];
                #pragma unroll
                for (int mi = 0; mi < 4; ++mi)
                    acc[mi][ni] = __builtin_amdgcn_mfma_f32_16x16x32_bf16(af[mi], bfr, acc[mi][ni], 0, 0, 0);
            }
        }
        __builtin_amdgcn_s_setprio(0);
        __syncthreads();                     // MFMA done; next build may overwrite
    }

    // ================= epilogue: BN + ReLU, float4 stores ===================
    #pragma unroll
    for (int ni = 0; ni < 2; ++ni) {
        int oc = oc0 + ni * 16 + l15;
        float inv   = 1.f / sqrtf(bn_var[oc] + 1e-5f);
        float scale = bn_gamma[oc] * inv;
        float shift = bn_beta[oc] - bn_mean[oc] * scale;
        float* op = out + ((size_t)b * OUTC + oc) * HW + h * WW + kg * 4;
        #pragma unroll
        for (int mi = 0; mi < 4; ++mi) {
            f32x4 o4;
            #pragma unroll
            for (int j = 0; j < 4; ++j) {
                float v = fmaf(acc[mi][ni][j], scale, shift);
                o4[j] = v > 0.f ? v : 0.f;
            }
            *(f32x4*)(op + mi * 16) = o4;
        }
    }
}

extern "C" void kernel_launch(void* const* d_in, const int* in_sizes, int n_in,
                              void* d_out, int out_size, void* d_ws, size_t ws_size,
                              hipStream_t stream) {
    (void)in_sizes; (void)n_in; (void)out_size; (void)d_ws; (void)ws_size;
    const float* x        = (const float*)d_in[0];
    const float* w_offset = (const float*)d_in[1];
    const float* b_offset = (const float*)d_in[2];
    const float* w_mask   = (const float*)d_in[3];
    const float* b_mask   = (const float*)d_in[4];
    const float* w_conv   = (const float*)d_in[5];
    const float* bn_gamma = (const float*)d_in[6];
    const float* bn_beta  = (const float*)d_in[7];
    const float* bn_mean  = (const float*)d_in[8];
    const float* bn_var   = (const float*)d_in[9];
    float* out = (float*)d_out;

    int prep_elems = 32 * KTOT + OUTC * KTOT;
    prep_kernel<<<(prep_elems + 255) / 256, 256, 0, stream>>>(w_offset, w_mask, w_conv);
    fused_kernel<<<BB * HH, 512, 0, stream>>>(x, b_offset, b_mask,
                                              bn_gamma, bn_beta, bn_mean, bn_var, out);
}